// Round 4
// baseline (1161.042 us; speedup 1.0000x reference)
//
#include <hip/hip_runtime.h>

typedef __attribute__((ext_vector_type(8))) short short8;
typedef __attribute__((ext_vector_type(8))) unsigned short u16x8;
typedef __attribute__((ext_vector_type(4))) float f32x4;

// ---------------- problem constants ----------------
constexpr int NTOK = 8192;
constexpr int DIM = 1024;
constexpr int HID = 4096;
constexpr int NE = 8;
constexpr int NG = NTOK * 2;          // grouped rows (top-2)
constexpr int NG_PAD = NG + 128;      // tile-pad slack

// ---------------- workspace layout (bytes) ----------------
constexpr size_t OFF_CNT   = 0;                     // int[8]   (zeroed)
constexpr size_t OFF_CUR   = 32;                    // int[8]   (zeroed)
constexpr size_t OFF_ENT   = 64;                    // float    (zeroed)
constexpr size_t OFF_IMP   = 68;                    // float[8] (zeroed)
constexpr size_t OFF_OFFS  = 128;                   // int[8]
constexpr size_t OFF_SEL   = 512;                                   // int[8192][2]
constexpr size_t OFF_GATE  = OFF_SEL  + (size_t)NTOK * 2 * 4;       // float[8192][2]
constexpr size_t OFF_RTOK  = OFF_GATE + (size_t)NTOK * 2 * 4;       // int[NG_PAD]
constexpr size_t OFF_RGATE = OFF_RTOK + (size_t)NG_PAD * 4;         // float[NG_PAD]
constexpr size_t OFF_XBF   = (OFF_RGATE + (size_t)NG_PAD * 4 + 511) & ~(size_t)511;
constexpr size_t OFF_W1T   = OFF_XBF + (size_t)NTOK * DIM * 2;      // bf16 [8][4096][1024]
constexpr size_t OFF_W2T   = OFF_W1T + (size_t)NE * HID * DIM * 2;  // bf16 [8][1024][4096]
constexpr size_t OFF_H     = OFF_W2T + (size_t)NE * DIM * HID * 2;  // bf16 [NG_PAD][4096]

__device__ __forceinline__ unsigned short f2bf(float f) {
    unsigned u = __float_as_uint(f);
    unsigned r = (u + 0x7fff + ((u >> 16) & 1)) >> 16;
    return (unsigned short)r;
}

__device__ __forceinline__ void gload16(const void* g, void* l) {
    __builtin_amdgcn_global_load_lds(
        (const __attribute__((address_space(1))) void*)g,
        (__attribute__((address_space(3))) void*)l, 16, 0, 0);
}

// ---------------- x f32 -> bf16 ----------------
__global__ __launch_bounds__(256) void k_cvt_x(const float* __restrict__ x,
                                               unsigned short* __restrict__ xbf) {
    size_t i = (size_t)blockIdx.x * 256 + threadIdx.x;   // 1,048,576 threads
    const float4* p = (const float4*)x + i * 2;
    float4 a = p[0], b = p[1];
    u16x8 o;
    o[0] = f2bf(a.x); o[1] = f2bf(a.y); o[2] = f2bf(a.z); o[3] = f2bf(a.w);
    o[4] = f2bf(b.x); o[5] = f2bf(b.y); o[6] = f2bf(b.z); o[7] = f2bf(b.w);
    *(u16x8*)&xbf[i * 8] = o;
}

// ---------------- per-expert transpose + convert: src f32 [R][C] -> dst bf16 [C][R] ----------------
__global__ __launch_bounds__(256) void k_transpose_cvt(const float* __restrict__ src,
                                                       unsigned short* __restrict__ dst,
                                                       int R, int C) {
    __shared__ __align__(16) unsigned short tile[64][65];
    int e = blockIdx.z;
    const float* S = src + (size_t)e * R * C;
    unsigned short* D = dst + (size_t)e * R * C;
    int c0 = blockIdx.x * 64, r0 = blockIdx.y * 64;
    int tid = threadIdx.x;
    int cc = (tid & 15) * 4, rr = tid >> 4;
#pragma unroll
    for (int it = 0; it < 4; ++it) {
        int r = rr + it * 16;
        float4 v = *(const float4*)&S[(size_t)(r0 + r) * C + c0 + cc];
        tile[cc + 0][r] = f2bf(v.x);
        tile[cc + 1][r] = f2bf(v.y);
        tile[cc + 2][r] = f2bf(v.z);
        tile[cc + 3][r] = f2bf(v.w);
    }
    __syncthreads();
    int rr2 = (tid & 15) * 4, ccw = tid >> 4;
#pragma unroll
    for (int it = 0; it < 4; ++it) {
        int c = ccw + it * 16;
        ushort4 o;
        o.x = tile[c][rr2 + 0]; o.y = tile[c][rr2 + 1];
        o.z = tile[c][rr2 + 2]; o.w = tile[c][rr2 + 3];
        *(ushort4*)&D[(size_t)(c0 + c) * R + r0 + rr2] = o;
    }
}

// ---------------- router: logits, top-2, gates, aux-loss partials ----------------
__global__ __launch_bounds__(256) void k_router(const float* __restrict__ x,
                                                const float* __restrict__ rw,
                                                const float* __restrict__ rb,
                                                int* __restrict__ sel,
                                                float* __restrict__ gates,
                                                int* __restrict__ counts,
                                                float* __restrict__ entsum,
                                                float* __restrict__ impsum) {
    __shared__ float rwt[8][1024];            // router_w transposed
    __shared__ float s_ent[4];
    __shared__ float s_imp[4][8];
    __shared__ int   s_cnt[4][8];
    int tid = threadIdx.x;
    for (int i = tid; i < 8192; i += 256)
        rwt[i >> 10][i & 1023] = rw[(size_t)(i & 1023) * 8 + (i >> 10)];
    __syncthreads();

    int lane = tid & 63, wave = tid >> 6;
    float ent_acc = 0.f, imp_acc[8];
    int cnt_acc[8];
#pragma unroll
    for (int e = 0; e < 8; ++e) { imp_acc[e] = 0.f; cnt_acc[e] = 0; }

    int wgid = blockIdx.x * 4 + wave;         // 0..2047
    for (int i = 0; i < 4; ++i) {
        int t = wgid * 4 + i;
        float acc[8];
#pragma unroll
        for (int e = 0; e < 8; ++e) acc[e] = 0.f;
        const float* xrow = x + (size_t)t * 1024;
#pragma unroll
        for (int c = 0; c < 4; ++c) {
            int k = c * 256 + lane * 4;
            float4 xv = *(const float4*)&xrow[k];
#pragma unroll
            for (int e = 0; e < 8; ++e) {
                float4 wv = *(const float4*)&rwt[e][k];
                acc[e] += xv.x * wv.x + xv.y * wv.y + xv.z * wv.z + xv.w * wv.w;
            }
        }
#pragma unroll
        for (int off = 32; off > 0; off >>= 1)
#pragma unroll
            for (int e = 0; e < 8; ++e) acc[e] += __shfl_xor(acc[e], off);

        float lg[8];
#pragma unroll
        for (int e = 0; e < 8; ++e) lg[e] = acc[e] + rb[e];

        // top-2 (ties -> lower index, like lax.top_k)
        int i1 = 0; float v1 = lg[0];
#pragma unroll
        for (int e = 1; e < 8; ++e) if (lg[e] > v1) { v1 = lg[e]; i1 = e; }
        int i2 = (i1 == 0) ? 1 : 0; float v2 = lg[i2];
#pragma unroll
        for (int e = 0; e < 8; ++e)
            if (e != i1 && e != i2 && lg[e] > v2) { v2 = lg[e]; i2 = e; }
        float g0 = 1.f / (1.f + expf(v2 - v1));
        float g1 = 1.f - g0;

        // full softmax, entropy, importance
        float s = 0.f, p[8];
#pragma unroll
        for (int e = 0; e < 8; ++e) { p[e] = expf(lg[e] - v1); s += p[e]; }
        float inv = 1.f / s, ent = 0.f;
#pragma unroll
        for (int e = 0; e < 8; ++e) {
            float pe = p[e] * inv;
            imp_acc[e] += pe;
            ent -= pe * logf(fmaxf(pe, 1e-8f));
        }
        ent_acc += ent;
        cnt_acc[i1]++; cnt_acc[i2]++;
        if (lane == 0) {
            sel[t * 2] = i1; sel[t * 2 + 1] = i2;
            gates[t * 2] = g0; gates[t * 2 + 1] = g1;
        }
    }
    if (lane == 0) {
        s_ent[wave] = ent_acc;
#pragma unroll
        for (int e = 0; e < 8; ++e) { s_imp[wave][e] = imp_acc[e]; s_cnt[wave][e] = cnt_acc[e]; }
    }
    __syncthreads();
    if (tid < 8) {
        float si = 0.f; int sc = 0;
        for (int w = 0; w < 4; ++w) { si += s_imp[w][tid]; sc += s_cnt[w][tid]; }
        atomicAdd(&impsum[tid], si);
        atomicAdd(&counts[tid], sc);
        if (tid == 0) {
            float se = 0.f;
            for (int w = 0; w < 4; ++w) se += s_ent[w];
            atomicAdd(entsum, se);
        }
    }
}

// ---------------- offsets + aux-loss scalars ----------------
__global__ void k_finalize(const int* __restrict__ counts, int* __restrict__ offs,
                           const float* __restrict__ entsum, const float* __restrict__ impsum,
                           float* __restrict__ out) {
    if (threadIdx.x == 0) {
        int o = 0;
        for (int e = 0; e < 8; ++e) { offs[e] = o; o += counts[e]; }
        out[(size_t)NTOK * DIM] = entsum[0] / (float)NTOK;
        float lb = 0.f;
        for (int e = 0; e < 8; ++e) {
            float d = impsum[e] / (float)NTOK - 1.f / (float)NE;
            lb += d * d;
        }
        out[(size_t)NTOK * DIM + 1] = lb / (float)NE;
    }
}

// ---------------- build grouped row lists (wave-aggregated atomics) ----------------
__global__ __launch_bounds__(256) void k_scatter(const int* __restrict__ sel,
                                                 const float* __restrict__ gates,
                                                 const int* __restrict__ offs,
                                                 int* __restrict__ cursor,
                                                 int* __restrict__ rowtok,
                                                 float* __restrict__ rowgate) {
    int t = blockIdx.x * 256 + threadIdx.x;
    int lane = threadIdx.x & 63;
#pragma unroll
    for (int s = 0; s < 2; ++s) {
        int e = sel[t * 2 + s];
        float g = gates[t * 2 + s];
        for (int ee = 0; ee < 8; ++ee) {
            unsigned long long mask = __ballot(e == ee);
            if (mask == 0ull) continue;
            int leader = __ffsll((unsigned long long)mask) - 1;
            int cnt = __popcll(mask);
            int base = 0;
            if (lane == leader) base = atomicAdd(&cursor[ee], cnt);
            base = __shfl(base, leader);
            if (e == ee) {
                int pos = base + __popcll(mask & ((1ull << lane) - 1ull));
                int gi = offs[ee] + pos;
                rowtok[gi] = t;
                rowgate[gi] = g;
            }
        }
    }
}

// ---------------- grouped GEMM 1: h = relu(gather(x) @ w1[e] + b1[e]) ----------------
__global__ __launch_bounds__(256) void k_ffn1(const unsigned short* __restrict__ xbf,
                                              const unsigned short* __restrict__ w1t,
                                              const float* __restrict__ b1,
                                              const int* __restrict__ rowtok,
                                              const int* __restrict__ offs,
                                              const int* __restrict__ cnts,
                                              unsigned short* __restrict__ h) {
    const int e = blockIdx.z;
    const int cnt = cnts[e];
    const int m0 = blockIdx.x * 128;
    if (m0 >= cnt) return;
    const int n0 = blockIdx.y * 128;
    const int off = offs[e];

    __shared__ __align__(16) unsigned short aL[128 * 32];
    __shared__ __align__(16) unsigned short bL[128 * 32];

    const int tid = threadIdx.x;
    const int lane = tid & 63;
    const int wave = tid >> 6;
    const int wm = (wave & 1) * 64;
    const int wn = (wave >> 1) * 64;

    const int srow = tid >> 2;
    const int scol = (tid & 3) * 8;
    const int r0 = srow, r1 = srow + 64;
    int t0 = (m0 + r0 < cnt) ? rowtok[off + m0 + r0] : rowtok[off];
    int t1 = (m0 + r1 < cnt) ? rowtok[off + m0 + r1] : rowtok[off];
    const unsigned short* sA0 = xbf + (size_t)t0 * DIM + scol;
    const unsigned short* sA1 = xbf + (size_t)t1 * DIM + scol;
    const unsigned short* wb = w1t + (size_t)e * HID * DIM;
    const unsigned short* sB0 = wb + (size_t)(n0 + r0) * DIM + scol;
    const unsigned short* sB1 = wb + (size_t)(n0 + r1) * DIM + scol;
    unsigned short* dA0 = aL + r0 * 32 + scol;
    unsigned short* dA1 = aL + r1 * 32 + scol;
    unsigned short* dB0 = bL + r0 * 32 + scol;
    unsigned short* dB1 = bL + r1 * 32 + scol;

    f32x4 acc[4][4];
#pragma unroll
    for (int mi = 0; mi < 4; ++mi)
#pragma unroll
        for (int ni = 0; ni < 4; ++ni) acc[mi][ni] = (f32x4){0.f, 0.f, 0.f, 0.f};

    const int koff = (lane >> 4) * 8;
    for (int k0 = 0; k0 < DIM; k0 += 32) {
        __syncthreads();
        gload16(sA0 + k0, dA0);
        gload16(sA1 + k0, dA1);
        gload16(sB0 + k0, dB0);
        gload16(sB1 + k0, dB1);
        __syncthreads();
        short8 af[4], bfr[4];
#pragma unroll
        for (int mi = 0; mi < 4; ++mi)
            af[mi] = *(const short8*)&aL[(wm + mi * 16 + (lane & 15)) * 32 + koff];
#pragma unroll
        for (int ni = 0; ni < 4; ++ni)
            bfr[ni] = *(const short8*)&bL[(wn + ni * 16 + (lane & 15)) * 32 + koff];
#pragma unroll
        for (int mi = 0; mi < 4; ++mi)
#pragma unroll
            for (int ni = 0; ni < 4; ++ni)
                acc[mi][ni] = __builtin_amdgcn_mfma_f32_16x16x32_bf16(af[mi], bfr[ni], acc[mi][ni], 0, 0, 0);
    }

#pragma unroll
    for (int mi = 0; mi < 4; ++mi) {
#pragma unroll
        for (int j = 0; j < 4; ++j) {
            int rl = wm + mi * 16 + (lane >> 4) * 4 + j;
            if (m0 + rl < cnt) {
                size_t hrow = (size_t)(off + m0 + rl) * HID;
#pragma unroll
                for (int ni = 0; ni < 4; ++ni) {
                    int col = n0 + wn + ni * 16 + (lane & 15);
                    float v = acc[mi][ni][j] + b1[e * HID + col];
                    h[hrow + col] = f2bf(fmaxf(v, 0.f));
                }
            }
        }
    }
}

// ---------------- grouped GEMM 2: out += gate * (h @ w2[e] + b2[e]) ----------------
__global__ __launch_bounds__(256) void k_ffn2(const unsigned short* __restrict__ h,
                                              const unsigned short* __restrict__ w2t,
                                              const float* __restrict__ b2,
                                              const int* __restrict__ rowtok,
                                              const float* __restrict__ rowgate,
                                              const int* __restrict__ offs,
                                              const int* __restrict__ cnts,
                                              float* __restrict__ out) {
    const int e = blockIdx.z;
    const int cnt = cnts[e];
    const int m0 = blockIdx.x * 128;
    if (m0 >= cnt) return;
    const int n0 = blockIdx.y * 128;
    const int off = offs[e];

    __shared__ __align__(16) unsigned short aL[128 * 32];
    __shared__ __align__(16) unsigned short bL[128 * 32];

    const int tid = threadIdx.x;
    const int lane = tid & 63;
    const int wave = tid >> 6;
    const int wm = (wave & 1) * 64;
    const int wn = (wave >> 1) * 64;

    const int srow = tid >> 2;
    const int scol = (tid & 3) * 8;
    const int r0 = srow, r1 = srow + 64;
    const unsigned short* sA0 = h + (size_t)(off + m0 + r0) * HID + scol;
    const unsigned short* sA1 = h + (size_t)(off + m0 + r1) * HID + scol;
    const unsigned short* wb = w2t + (size_t)e * DIM * HID;
    const unsigned short* sB0 = wb + (size_t)(n0 + r0) * HID + scol;
    const unsigned short* sB1 = wb + (size_t)(n0 + r1) * HID + scol;
    unsigned short* dA0 = aL + r0 * 32 + scol;
    unsigned short* dA1 = aL + r1 * 32 + scol;
    unsigned short* dB0 = bL + r0 * 32 + scol;
    unsigned short* dB1 = bL + r1 * 32 + scol;

    f32x4 acc[4][4];
#pragma unroll
    for (int mi = 0; mi < 4; ++mi)
#pragma unroll
        for (int ni = 0; ni < 4; ++ni) acc[mi][ni] = (f32x4){0.f, 0.f, 0.f, 0.f};

    const int koff = (lane >> 4) * 8;
    for (int k0 = 0; k0 < HID; k0 += 32) {
        __syncthreads();
        gload16(sA0 + k0, dA0);
        gload16(sA1 + k0, dA1);
        gload16(sB0 + k0, dB0);
        gload16(sB1 + k0, dB1);
        __syncthreads();
        short8 af[4], bfr[4];
#pragma unroll
        for (int mi = 0; mi < 4; ++mi)
            af[mi] = *(const short8*)&aL[(wm + mi * 16 + (lane & 15)) * 32 + koff];
#pragma unroll
        for (int ni = 0; ni < 4; ++ni)
            bfr[ni] = *(const short8*)&bL[(wn + ni * 16 + (lane & 15)) * 32 + koff];
#pragma unroll
        for (int mi = 0; mi < 4; ++mi)
#pragma unroll
            for (int ni = 0; ni < 4; ++ni)
                acc[mi][ni] = __builtin_amdgcn_mfma_f32_16x16x32_bf16(af[mi], bfr[ni], acc[mi][ni], 0, 0, 0);
    }

#pragma unroll
    for (int mi = 0; mi < 4; ++mi) {
#pragma unroll
        for (int j = 0; j < 4; ++j) {
            int rl = wm + mi * 16 + (lane >> 4) * 4 + j;
            if (m0 + rl < cnt) {
                int g = off + m0 + rl;
                int tk = rowtok[g];
                float gate = rowgate[g];
#pragma unroll
                for (int ni = 0; ni < 4; ++ni) {
                    int col = n0 + wn + ni * 16 + (lane & 15);
                    float v = (acc[mi][ni][j] + b2[e * DIM + col]) * gate;
                    unsafeAtomicAdd(&out[(size_t)tk * DIM + col], v);
                }
            }
        }
    }
}

// ---------------- launch ----------------
extern "C" void kernel_launch(void* const* d_in, const int* in_sizes, int n_in,
                              void* d_out, int out_size, void* d_ws, size_t ws_size,
                              hipStream_t stream) {
    const float* x  = (const float*)d_in[0];
    const float* rw = (const float*)d_in[1];
    const float* rb = (const float*)d_in[2];
    const float* w1 = (const float*)d_in[3];
    const float* b1 = (const float*)d_in[4];
    const float* w2 = (const float*)d_in[5];
    const float* b2 = (const float*)d_in[6];
    float* out = (float*)d_out;
    char* ws = (char*)d_ws;

    int*   counts  = (int*)(ws + OFF_CNT);
    int*   cursor  = (int*)(ws + OFF_CUR);
    float* entsum  = (float*)(ws + OFF_ENT);
    float* impsum  = (float*)(ws + OFF_IMP);
    int*   offs    = (int*)(ws + OFF_OFFS);
    int*   sel     = (int*)(ws + OFF_SEL);
    float* gates   = (float*)(ws + OFF_GATE);
    int*   rowtok  = (int*)(ws + OFF_RTOK);
    float* rowgate = (float*)(ws + OFF_RGATE);
    unsigned short* xbf = (unsigned short*)(ws + OFF_XBF);
    unsigned short* w1t = (unsigned short*)(ws + OFF_W1T);
    unsigned short* w2t = (unsigned short*)(ws + OFF_W2T);
    unsigned short* hbuf = (unsigned short*)(ws + OFF_H);

    hipMemsetAsync(ws, 0, 128, stream);
    hipMemsetAsync(d_out, 0, (size_t)out_size * sizeof(float), stream);

    k_cvt_x<<<4096, 256, 0, stream>>>(x, xbf);
    k_transpose_cvt<<<dim3(HID / 64, DIM / 64, NE), 256, 0, stream>>>(w1, w1t, DIM, HID);
    k_transpose_cvt<<<dim3(DIM / 64, HID / 64, NE), 256, 0, stream>>>(w2, w2t, HID, DIM);

    k_router<<<512, 256, 0, stream>>>(x, rw, rb, sel, gates, counts, entsum, impsum);
    k_finalize<<<1, 64, 0, stream>>>(counts, offs, entsum, impsum, out);
    k_scatter<<<32, 256, 0, stream>>>(sel, gates, offs, cursor, rowtok, rowgate);

    k_ffn1<<<dim3(64, HID / 128, NE), 256, 0, stream>>>(xbf, w1t, b1, rowtok, offs, counts, hbuf);
    k_ffn2<<<dim3(64, DIM / 128, NE), 256, 0, stream>>>(hbuf, w2t, b2, rowtok, rowgate, offs, counts, out);
}